// Round 1
// baseline (477.192 us; speedup 1.0000x reference)
//
#include <hip/hip_runtime.h>
#include <cstdint>

#define L_NUM 12
#define B_NUM 1024
#define P_NUM 100
#define LP_NUM 8
#define D_NUM 768
#define TILE_E (LP_NUM * D_NUM)   // 6144 floats per (l,b) output tile
#define TOPK 5
#define GQ 8                      // queries per block in scores kernel
#define EPSF 1e-12f
#define NTILE (L_NUM * B_NUM)     // 12288 (l,b) tiles

typedef float f32x4 __attribute__((ext_vector_type(4)));

// monotonic key: larger score -> larger key; ties -> lower index wins
__device__ __forceinline__ unsigned long long makeKey(float f, int p) {
    union { float f; uint32_t u; } v; v.f = f;
    uint32_t u = v.u;
    u = (u & 0x80000000u) ? ~u : (u | 0x80000000u);
    return ((unsigned long long)u << 32) | (unsigned)(127 - p);
}

// ---- Kernel 1: per-(l,p) stats: invK = 1/max(||K||,eps), s = <Kn, An> ----
__global__ __launch_bounds__(64) void proto_stats_kernel(
    const float* __restrict__ K, const float* __restrict__ A,
    float* __restrict__ invK, float* __restrict__ sArr)
{
    const int lp = blockIdx.x;          // l*P_NUM + p
    const int lane = threadIdx.x;
    const float4* Kp = (const float4*)(K + (size_t)lp * D_NUM);
    const float4* Ap = (const float4*)(A + (size_t)lp * D_NUM);
    float kk = 0.f, aa = 0.f, ka = 0.f;
#pragma unroll
    for (int c = 0; c < 3; c++) {
        float4 k4 = Kp[c * 64 + lane];
        float4 a4 = Ap[c * 64 + lane];
        kk += k4.x * k4.x + k4.y * k4.y + k4.z * k4.z + k4.w * k4.w;
        aa += a4.x * a4.x + a4.y * a4.y + a4.z * a4.z + a4.w * a4.w;
        ka += k4.x * a4.x + k4.y * a4.y + k4.z * a4.z + k4.w * a4.w;
    }
#pragma unroll
    for (int off = 32; off; off >>= 1) {
        kk += __shfl_xor(kk, off);
        aa += __shfl_xor(aa, off);
        ka += __shfl_xor(ka, off);
    }
    if (lane == 0) {
        float nk = fmaxf(sqrtf(kk), EPSF);
        float na = fmaxf(sqrtf(aa), EPSF);
        invK[lp] = 1.0f / nk;
        sArr[lp] = ka / (nk * na);
    }
}

// ---- Kernel 2: scores + top-5 -> idx/wgt workspace (no gather here) ----
__global__ __launch_bounds__(256) void scores_topk_kernel(
    const float* __restrict__ X,     // [B, L, D]
    const float* __restrict__ K,     // [L, P, D]
    const float* __restrict__ invK,  // [L*P]
    const float* __restrict__ sArr,  // [L*P]
    int*   __restrict__ idxW,        // [L*B*TOPK]
    float* __restrict__ wgtW)        // [L*B*TOPK]
{
    const int b0 = blockIdx.x * GQ;
    const int l  = blockIdx.y;
    const int tid = threadIdx.x;
    const int lane = tid & 63;
    const int w = tid >> 6;           // wave 0..3

    __shared__ float sc[GQ][P_NUM];

    // ---- phase 1: scores. GQ query rows in registers (float4-chunked). ----
    float4 q[GQ][3];
#pragma unroll
    for (int g = 0; g < GQ; g++) {
        const float4* Q = (const float4*)(X + ((size_t)(b0 + g) * L_NUM + l) * D_NUM);
#pragma unroll
        for (int c = 0; c < 3; c++) q[g][c] = Q[c * 64 + lane];
    }

    // each wave: 25 prototypes; dot against all GQ queries
    for (int i = 0; i < 25; i++) {
        const int p = w * 25 + i;
        const float4* Kp = (const float4*)(K + ((size_t)l * P_NUM + p) * D_NUM);
        float4 kv0 = Kp[0 * 64 + lane];
        float4 kv1 = Kp[1 * 64 + lane];
        float4 kv2 = Kp[2 * 64 + lane];
        float acc[GQ];
#pragma unroll
        for (int g = 0; g < GQ; g++) {
            acc[g] = q[g][0].x * kv0.x + q[g][0].y * kv0.y + q[g][0].z * kv0.z + q[g][0].w * kv0.w
                   + q[g][1].x * kv1.x + q[g][1].y * kv1.y + q[g][1].z * kv1.z + q[g][1].w * kv1.w
                   + q[g][2].x * kv2.x + q[g][2].y * kv2.y + q[g][2].z * kv2.z + q[g][2].w * kv2.w;
        }
#pragma unroll
        for (int off = 32; off; off >>= 1) {
#pragma unroll
            for (int g = 0; g < GQ; g++) acc[g] += __shfl_xor(acc[g], off);
        }
        if (lane == 0) {
            const float s = invK[l * P_NUM + p];
#pragma unroll
            for (int g = 0; g < GQ; g++) sc[g][p] = acc[g] * s;
        }
    }
    __syncthreads();

    // ---- phase 2: top-5 per query (wave w handles g = w and g = w+4),
    //      lane 0 writes idx/wgt straight to workspace (no LDS, no barrier)
#pragma unroll
    for (int pass = 0; pass < 2; pass++) {
        const int g = w + pass * 4;
        float s0 = sc[g][lane];
        float s1 = (lane + 64 < P_NUM) ? sc[g][lane + 64] : -3.0e38f;
        unsigned long long k0 = makeKey(s0, lane);
        unsigned long long k1 = makeKey(s1, lane + 64);
        for (int j = 0; j < TOPK; j++) {
            unsigned long long m = k0 > k1 ? k0 : k1;
#pragma unroll
            for (int off = 32; off; off >>= 1) {
                unsigned long long o = __shfl_xor(m, off);
                if (o > m) m = o;
            }
            if (k0 == m) k0 = 0ull;
            if (k1 == m) k1 = 0ull;
            if (lane == 0) {
                int p = 127 - (int)(m & 127ull);
                size_t o = ((size_t)l * B_NUM + (b0 + g)) * TOPK + j;
                idxW[o] = p;
                wgtW[o] = sArr[l * P_NUM + p];
            }
        }
    }
}

// ---- Kernel 3: weighted gather-out. One block per (l,b) tile.
//      XCD-swizzled so each XCD's resident blocks share one l-slice of P
//      (2.45 MB < 4 MB per-XCD L2). Output stored nontemporal so the
//      302 MB write stream doesn't evict P from L2.
__global__ __launch_bounds__(256) void gather_kernel(
    const float* __restrict__ Pall,  // [L, P, Lp, D]
    const int*   __restrict__ idxW,  // [L*B*TOPK]
    const float* __restrict__ wgtW,  // [L*B*TOPK]
    float* __restrict__ out)         // [L, B, Lp, D]
{
    const int i = blockIdx.x;
    // round-robin wg->XCD assumption: XCD j runs i % 8 == j in launch order.
    // Give XCD j a contiguous range of tiles -> l changes rarely per XCD.
    const int t = (i & 7) * (NTILE / 8) + (i >> 3);   // tile = l*B + b
    const int l = t / B_NUM;
    const int tid = threadIdx.x;

    const float* Pl = Pall + (size_t)l * P_NUM * TILE_E;
    const size_t base = (size_t)t * TOPK;

    const f32x4* Pr[TOPK];
    float wk[TOPK];
#pragma unroll
    for (int j = 0; j < TOPK; j++) {
        Pr[j] = (const f32x4*)(Pl + (size_t)idxW[base + j] * TILE_E);
        wk[j] = wgtW[base + j];
    }

    f32x4* outv = (f32x4*)(out + (size_t)t * TILE_E);
    // 6144 floats = 1536 float4; 256 threads x 6 iterations
#pragma unroll 2
    for (int it = 0; it < 6; it++) {
        const int e4 = it * 256 + tid;
        f32x4 r = {0.f, 0.f, 0.f, 0.f};
#pragma unroll
        for (int j = 0; j < TOPK; j++) {
            f32x4 pu = Pr[j][e4];
            r += wk[j] * pu;
        }
        __builtin_nontemporal_store(r, &outv[e4]);
    }
}

extern "C" void kernel_launch(void* const* d_in, const int* in_sizes, int n_in,
                              void* d_out, int out_size, void* d_ws, size_t ws_size,
                              hipStream_t stream) {
    const float* X  = (const float*)d_in[0];  // x_query [B,L,D]
    const float* K  = (const float*)d_in[1];  // K_all   [L,P,D]
    const float* A  = (const float*)d_in[2];  // A_all   [L,P,D]
    const float* Pp = (const float*)d_in[3];  // P_all   [L,P,Lp,D]

    float* invK = (float*)d_ws;                   // 1200 floats
    float* sArr = invK + L_NUM * P_NUM;           // 1200 floats
    int*   idxW = (int*)(sArr + L_NUM * P_NUM);   // 61440 ints
    float* wgtW = (float*)(idxW + NTILE * TOPK);  // 61440 floats

    proto_stats_kernel<<<L_NUM * P_NUM, 64, 0, stream>>>(K, A, invK, sArr);
    scores_topk_kernel<<<dim3(B_NUM / GQ, L_NUM), 256, 0, stream>>>(
        X, K, invK, sArr, idxW, wgtW);
    gather_kernel<<<NTILE, 256, 0, stream>>>(Pp, idxW, wgtW, (float*)d_out);
}

// Round 2
// 461.241 us; speedup vs baseline: 1.0346x; 1.0346x over previous
//
#include <hip/hip_runtime.h>
#include <cstdint>

#define L_NUM 12
#define B_NUM 1024
#define P_NUM 100
#define LP_NUM 8
#define D_NUM 768
#define TILE_E (LP_NUM * D_NUM)   // 6144 floats per (l,b) output tile
#define TOPK 5
#define GQ 8                      // queries per block in scores kernel
#define EPSF 1e-12f
#define NTILE (L_NUM * B_NUM)     // 12288 (l,b) tiles

typedef float f32x4 __attribute__((ext_vector_type(4)));

// monotonic key: larger score -> larger key; ties -> lower index wins
__device__ __forceinline__ unsigned long long makeKey(float f, int p) {
    union { float f; uint32_t u; } v; v.f = f;
    uint32_t u = v.u;
    u = (u & 0x80000000u) ? ~u : (u | 0x80000000u);
    return ((unsigned long long)u << 32) | (unsigned)(127 - p);
}

// ---- Kernel 1: per-(l,p) stats: invK = 1/max(||K||,eps), s = <Kn, An> ----
__global__ __launch_bounds__(64) void proto_stats_kernel(
    const float* __restrict__ K, const float* __restrict__ A,
    float* __restrict__ invK, float* __restrict__ sArr)
{
    const int lp = blockIdx.x;          // l*P_NUM + p
    const int lane = threadIdx.x;
    const float4* Kp = (const float4*)(K + (size_t)lp * D_NUM);
    const float4* Ap = (const float4*)(A + (size_t)lp * D_NUM);
    float kk = 0.f, aa = 0.f, ka = 0.f;
#pragma unroll
    for (int c = 0; c < 3; c++) {
        float4 k4 = Kp[c * 64 + lane];
        float4 a4 = Ap[c * 64 + lane];
        kk += k4.x * k4.x + k4.y * k4.y + k4.z * k4.z + k4.w * k4.w;
        aa += a4.x * a4.x + a4.y * a4.y + a4.z * a4.z + a4.w * a4.w;
        ka += k4.x * a4.x + k4.y * a4.y + k4.z * a4.z + k4.w * a4.w;
    }
#pragma unroll
    for (int off = 32; off; off >>= 1) {
        kk += __shfl_xor(kk, off);
        aa += __shfl_xor(aa, off);
        ka += __shfl_xor(ka, off);
    }
    if (lane == 0) {
        float nk = fmaxf(sqrtf(kk), EPSF);
        float na = fmaxf(sqrtf(aa), EPSF);
        invK[lp] = 1.0f / nk;
        sArr[lp] = ka / (nk * na);
    }
}

// ---- Kernel 2: scores + top-5 -> idx/wgt workspace (no gather here) ----
__global__ __launch_bounds__(256) void scores_topk_kernel(
    const float* __restrict__ X,     // [B, L, D]
    const float* __restrict__ K,     // [L, P, D]
    const float* __restrict__ invK,  // [L*P]
    const float* __restrict__ sArr,  // [L*P]
    int*   __restrict__ idxW,        // [L*B*TOPK]
    float* __restrict__ wgtW)        // [L*B*TOPK]
{
    const int b0 = blockIdx.x * GQ;
    const int l  = blockIdx.y;
    const int tid = threadIdx.x;
    const int lane = tid & 63;
    const int w = tid >> 6;           // wave 0..3

    __shared__ float sc[GQ][P_NUM];

    // ---- phase 1: scores. GQ query rows in registers (float4-chunked). ----
    float4 q[GQ][3];
#pragma unroll
    for (int g = 0; g < GQ; g++) {
        const float4* Q = (const float4*)(X + ((size_t)(b0 + g) * L_NUM + l) * D_NUM);
#pragma unroll
        for (int c = 0; c < 3; c++) q[g][c] = Q[c * 64 + lane];
    }

    // each wave: 25 prototypes; dot against all GQ queries
    for (int i = 0; i < 25; i++) {
        const int p = w * 25 + i;
        const float4* Kp = (const float4*)(K + ((size_t)l * P_NUM + p) * D_NUM);
        float4 kv0 = Kp[0 * 64 + lane];
        float4 kv1 = Kp[1 * 64 + lane];
        float4 kv2 = Kp[2 * 64 + lane];
        float acc[GQ];
#pragma unroll
        for (int g = 0; g < GQ; g++) {
            acc[g] = q[g][0].x * kv0.x + q[g][0].y * kv0.y + q[g][0].z * kv0.z + q[g][0].w * kv0.w
                   + q[g][1].x * kv1.x + q[g][1].y * kv1.y + q[g][1].z * kv1.z + q[g][1].w * kv1.w
                   + q[g][2].x * kv2.x + q[g][2].y * kv2.y + q[g][2].z * kv2.z + q[g][2].w * kv2.w;
        }
#pragma unroll
        for (int off = 32; off; off >>= 1) {
#pragma unroll
            for (int g = 0; g < GQ; g++) acc[g] += __shfl_xor(acc[g], off);
        }
        if (lane == 0) {
            const float s = invK[l * P_NUM + p];
#pragma unroll
            for (int g = 0; g < GQ; g++) sc[g][p] = acc[g] * s;
        }
    }
    __syncthreads();

    // ---- phase 2: top-5 per query (wave w handles g = w and g = w+4),
    //      lane 0 writes idx/wgt straight to workspace (no LDS, no barrier)
#pragma unroll
    for (int pass = 0; pass < 2; pass++) {
        const int g = w + pass * 4;
        float s0 = sc[g][lane];
        float s1 = (lane + 64 < P_NUM) ? sc[g][lane + 64] : -3.0e38f;
        unsigned long long k0 = makeKey(s0, lane);
        unsigned long long k1 = makeKey(s1, lane + 64);
        for (int j = 0; j < TOPK; j++) {
            unsigned long long m = k0 > k1 ? k0 : k1;
#pragma unroll
            for (int off = 32; off; off >>= 1) {
                unsigned long long o = __shfl_xor(m, off);
                if (o > m) m = o;
            }
            if (k0 == m) k0 = 0ull;
            if (k1 == m) k1 = 0ull;
            if (lane == 0) {
                int p = 127 - (int)(m & 127ull);
                size_t o = ((size_t)l * B_NUM + (b0 + g)) * TOPK + j;
                idxW[o] = p;
                wgtW[o] = sArr[l * P_NUM + p];
            }
        }
    }
}

// ---- Kernel 3: weighted gather-out. One block per (l,b) tile.
//      XCD-swizzled so each XCD's resident blocks share one l-slice of P
//      (2.45 MB, L2-resident). Output stored nontemporal so the 302 MB
//      write stream doesn't evict P from L2.
//      j-outer, fully-unrolled accumulation: all 30 float4 loads are
//      independent and issue early (MLP hides L2 latency).
__global__ __launch_bounds__(256) void gather_kernel(
    const float* __restrict__ Pall,  // [L, P, Lp, D]
    const int*   __restrict__ idxW,  // [L*B*TOPK]
    const float* __restrict__ wgtW,  // [L*B*TOPK]
    float* __restrict__ out)         // [L, B, Lp, D]
{
    const int i = blockIdx.x;
    // round-robin wg->XCD assumption: XCD j runs i % 8 == j in launch order.
    // Give XCD j a contiguous range of tiles -> l changes rarely per XCD.
    const int t = (i & 7) * (NTILE / 8) + (i >> 3);   // tile = l*B + b
    const int l = t / B_NUM;
    const int tid = threadIdx.x;

    const float* Pl = Pall + (size_t)l * P_NUM * TILE_E;
    const size_t base = (size_t)t * TOPK;

    const f32x4* Pr[TOPK];
    float wk[TOPK];
#pragma unroll
    for (int j = 0; j < TOPK; j++) {
        Pr[j] = (const f32x4*)(Pl + (size_t)idxW[base + j] * TILE_E);
        wk[j] = wgtW[base + j];
    }

    f32x4* outv = (f32x4*)(out + (size_t)t * TILE_E);

    f32x4 r[6];
#pragma unroll
    for (int it = 0; it < 6; it++) r[it] = (f32x4){0.f, 0.f, 0.f, 0.f};

#pragma unroll
    for (int j = 0; j < TOPK; j++) {
        const f32x4* Pj = Pr[j];
        const float wj = wk[j];
        f32x4 pu[6];
#pragma unroll
        for (int it = 0; it < 6; it++) pu[it] = Pj[it * 256 + tid];
#pragma unroll
        for (int it = 0; it < 6; it++) r[it] += wj * pu[it];
    }

#pragma unroll
    for (int it = 0; it < 6; it++)
        __builtin_nontemporal_store(r[it], &outv[it * 256 + tid]);
}

extern "C" void kernel_launch(void* const* d_in, const int* in_sizes, int n_in,
                              void* d_out, int out_size, void* d_ws, size_t ws_size,
                              hipStream_t stream) {
    const float* X  = (const float*)d_in[0];  // x_query [B,L,D]
    const float* K  = (const float*)d_in[1];  // K_all   [L,P,D]
    const float* A  = (const float*)d_in[2];  // A_all   [L,P,D]
    const float* Pp = (const float*)d_in[3];  // P_all   [L,P,Lp,D]

    float* invK = (float*)d_ws;                   // 1200 floats
    float* sArr = invK + L_NUM * P_NUM;           // 1200 floats
    int*   idxW = (int*)(sArr + L_NUM * P_NUM);   // 61440 ints
    float* wgtW = (float*)(idxW + NTILE * TOPK);  // 61440 floats

    proto_stats_kernel<<<L_NUM * P_NUM, 64, 0, stream>>>(K, A, invK, sArr);
    scores_topk_kernel<<<dim3(B_NUM / GQ, L_NUM), 256, 0, stream>>>(
        X, K, invK, sArr, idxW, wgtW);
    gather_kernel<<<NTILE, 256, 0, stream>>>(Pp, idxW, wgtW, (float*)d_out);
}

// Round 3
// 421.098 us; speedup vs baseline: 1.1332x; 1.0953x over previous
//
#include <hip/hip_runtime.h>
#include <cstdint>

#define L_NUM 12
#define B_NUM 1024
#define P_NUM 100
#define LP_NUM 8
#define D_NUM 768
#define TILE_E (LP_NUM * D_NUM)   // 6144 floats per (l,b) output tile
#define TOPK 5
#define GQ 8                      // queries per block in scores kernel
#define EPSF 1e-12f
#define NTILE (L_NUM * B_NUM)     // 12288 (l,b) tiles

typedef float f32x4 __attribute__((ext_vector_type(4)));

// monotonic key: larger score -> larger key; ties -> lower index wins
__device__ __forceinline__ unsigned long long makeKey(float f, int p) {
    union { float f; uint32_t u; } v; v.f = f;
    uint32_t u = v.u;
    u = (u & 0x80000000u) ? ~u : (u | 0x80000000u);
    return ((unsigned long long)u << 32) | (unsigned)(127 - p);
}

// ---- Kernel 1: per-(l,p) stats: invK = 1/max(||K||,eps), s = <Kn, An> ----
__global__ __launch_bounds__(64) void proto_stats_kernel(
    const float* __restrict__ K, const float* __restrict__ A,
    float* __restrict__ invK, float* __restrict__ sArr)
{
    const int lp = blockIdx.x;          // l*P_NUM + p
    const int lane = threadIdx.x;
    const float4* Kp = (const float4*)(K + (size_t)lp * D_NUM);
    const float4* Ap = (const float4*)(A + (size_t)lp * D_NUM);
    float kk = 0.f, aa = 0.f, ka = 0.f;
#pragma unroll
    for (int c = 0; c < 3; c++) {
        float4 k4 = Kp[c * 64 + lane];
        float4 a4 = Ap[c * 64 + lane];
        kk += k4.x * k4.x + k4.y * k4.y + k4.z * k4.z + k4.w * k4.w;
        aa += a4.x * a4.x + a4.y * a4.y + a4.z * a4.z + a4.w * a4.w;
        ka += k4.x * a4.x + k4.y * a4.y + k4.z * a4.z + k4.w * a4.w;
    }
#pragma unroll
    for (int off = 32; off; off >>= 1) {
        kk += __shfl_xor(kk, off);
        aa += __shfl_xor(aa, off);
        ka += __shfl_xor(ka, off);
    }
    if (lane == 0) {
        float nk = fmaxf(sqrtf(kk), EPSF);
        float na = fmaxf(sqrtf(aa), EPSF);
        invK[lp] = 1.0f / nk;
        sArr[lp] = ka / (nk * na);
    }
}

// ---- Kernel 2: scores + top-5 -> idx/wgt workspace (no gather here) ----
__global__ __launch_bounds__(256) void scores_topk_kernel(
    const float* __restrict__ X,     // [B, L, D]
    const float* __restrict__ K,     // [L, P, D]
    const float* __restrict__ invK,  // [L*P]
    const float* __restrict__ sArr,  // [L*P]
    int*   __restrict__ idxW,        // [L*B*TOPK]
    float* __restrict__ wgtW)        // [L*B*TOPK]
{
    const int b0 = blockIdx.x * GQ;
    const int l  = blockIdx.y;
    const int tid = threadIdx.x;
    const int lane = tid & 63;
    const int w = tid >> 6;           // wave 0..3

    __shared__ float sc[GQ][P_NUM];

    // ---- phase 1: scores. GQ query rows in registers (float4-chunked). ----
    float4 q[GQ][3];
#pragma unroll
    for (int g = 0; g < GQ; g++) {
        const float4* Q = (const float4*)(X + ((size_t)(b0 + g) * L_NUM + l) * D_NUM);
#pragma unroll
        for (int c = 0; c < 3; c++) q[g][c] = Q[c * 64 + lane];
    }

    // each wave: 25 prototypes; dot against all GQ queries
    for (int i = 0; i < 25; i++) {
        const int p = w * 25 + i;
        const float4* Kp = (const float4*)(K + ((size_t)l * P_NUM + p) * D_NUM);
        float4 kv0 = Kp[0 * 64 + lane];
        float4 kv1 = Kp[1 * 64 + lane];
        float4 kv2 = Kp[2 * 64 + lane];
        float acc[GQ];
#pragma unroll
        for (int g = 0; g < GQ; g++) {
            acc[g] = q[g][0].x * kv0.x + q[g][0].y * kv0.y + q[g][0].z * kv0.z + q[g][0].w * kv0.w
                   + q[g][1].x * kv1.x + q[g][1].y * kv1.y + q[g][1].z * kv1.z + q[g][1].w * kv1.w
                   + q[g][2].x * kv2.x + q[g][2].y * kv2.y + q[g][2].z * kv2.z + q[g][2].w * kv2.w;
        }

        // multi-value butterfly: fold the 8 accumulators into the tree.
        // 17 shuffles instead of 48. After the tree, lane holds the full
        // 64-lane sum for query g = bits[5:3] of lane = (lane>>3) at lanes
        // where (lane&7)==0.
        float r4[4];
#pragma unroll
        for (int g = 0; g < 4; g++) {
            float t0 = acc[g]     + __shfl_xor(acc[g],     32);
            float t1 = acc[g + 4] + __shfl_xor(acc[g + 4], 32);
            r4[g] = (lane & 32) ? t1 : t0;
        }
        float r2[2];
#pragma unroll
        for (int g = 0; g < 2; g++) {
            float t0 = r4[g]     + __shfl_xor(r4[g],     16);
            float t1 = r4[g + 2] + __shfl_xor(r4[g + 2], 16);
            r2[g] = (lane & 16) ? t1 : t0;
        }
        {
            float t0 = r2[0] + __shfl_xor(r2[0], 8);
            float t1 = r2[1] + __shfl_xor(r2[1], 8);
            float rr = (lane & 8) ? t1 : t0;
            rr += __shfl_xor(rr, 4);
            rr += __shfl_xor(rr, 2);
            rr += __shfl_xor(rr, 1);
            if ((lane & 7) == 0) {
                const float s = invK[l * P_NUM + p];
                sc[lane >> 3][p] = rr * s;   // banks (100*g+p)%32 all distinct
            }
        }
    }
    __syncthreads();

    // ---- phase 2: top-5 per query (wave w handles g = w and g = w+4),
    //      lane 0 writes idx/wgt straight to workspace (no LDS, no barrier)
#pragma unroll
    for (int pass = 0; pass < 2; pass++) {
        const int g = w + pass * 4;
        float s0 = sc[g][lane];
        float s1 = (lane + 64 < P_NUM) ? sc[g][lane + 64] : -3.0e38f;
        unsigned long long k0 = makeKey(s0, lane);
        unsigned long long k1 = makeKey(s1, lane + 64);
        for (int j = 0; j < TOPK; j++) {
            unsigned long long m = k0 > k1 ? k0 : k1;
#pragma unroll
            for (int off = 32; off; off >>= 1) {
                unsigned long long o = __shfl_xor(m, off);
                if (o > m) m = o;
            }
            if (k0 == m) k0 = 0ull;
            if (k1 == m) k1 = 0ull;
            if (lane == 0) {
                int p = 127 - (int)(m & 127ull);
                size_t o = ((size_t)l * B_NUM + (b0 + g)) * TOPK + j;
                idxW[o] = p;
                wgtW[o] = sArr[l * P_NUM + p];
            }
        }
    }
}

// ---- Kernel 3: weighted gather-out. One block per (l,b) tile.
//      XCD-swizzled so each XCD's resident blocks share one l-slice of P
//      (2.45 MB, L2-resident). Output stored nontemporal so the 302 MB
//      write stream doesn't evict P from L2.
//      j-outer, fully-unrolled accumulation: all 30 float4 loads are
//      independent and issue early (MLP hides L2 latency).
__global__ __launch_bounds__(256) void gather_kernel(
    const float* __restrict__ Pall,  // [L, P, Lp, D]
    const int*   __restrict__ idxW,  // [L*B*TOPK]
    const float* __restrict__ wgtW,  // [L*B*TOPK]
    float* __restrict__ out)         // [L, B, Lp, D]
{
    const int i = blockIdx.x;
    // round-robin wg->XCD assumption: XCD j runs i % 8 == j in launch order.
    // Give XCD j a contiguous range of tiles -> l changes rarely per XCD.
    const int t = (i & 7) * (NTILE / 8) + (i >> 3);   // tile = l*B + b
    const int l = t / B_NUM;
    const int tid = threadIdx.x;

    const float* Pl = Pall + (size_t)l * P_NUM * TILE_E;
    const size_t base = (size_t)t * TOPK;

    const f32x4* Pr[TOPK];
    float wk[TOPK];
#pragma unroll
    for (int j = 0; j < TOPK; j++) {
        Pr[j] = (const f32x4*)(Pl + (size_t)idxW[base + j] * TILE_E);
        wk[j] = wgtW[base + j];
    }

    f32x4* outv = (f32x4*)(out + (size_t)t * TILE_E);

    f32x4 r[6];
#pragma unroll
    for (int it = 0; it < 6; it++) r[it] = (f32x4){0.f, 0.f, 0.f, 0.f};

#pragma unroll
    for (int j = 0; j < TOPK; j++) {
        const f32x4* Pj = Pr[j];
        const float wj = wk[j];
        f32x4 pu[6];
#pragma unroll
        for (int it = 0; it < 6; it++) pu[it] = Pj[it * 256 + tid];
#pragma unroll
        for (int it = 0; it < 6; it++) r[it] += wj * pu[it];
    }

#pragma unroll
    for (int it = 0; it < 6; it++)
        __builtin_nontemporal_store(r[it], &outv[it * 256 + tid]);
}

extern "C" void kernel_launch(void* const* d_in, const int* in_sizes, int n_in,
                              void* d_out, int out_size, void* d_ws, size_t ws_size,
                              hipStream_t stream) {
    const float* X  = (const float*)d_in[0];  // x_query [B,L,D]
    const float* K  = (const float*)d_in[1];  // K_all   [L,P,D]
    const float* A  = (const float*)d_in[2];  // A_all   [L,P,D]
    const float* Pp = (const float*)d_in[3];  // P_all   [L,P,Lp,D]

    float* invK = (float*)d_ws;                   // 1200 floats
    float* sArr = invK + L_NUM * P_NUM;           // 1200 floats
    int*   idxW = (int*)(sArr + L_NUM * P_NUM);   // 61440 ints
    float* wgtW = (float*)(idxW + NTILE * TOPK);  // 61440 floats

    proto_stats_kernel<<<L_NUM * P_NUM, 64, 0, stream>>>(K, A, invK, sArr);
    scores_topk_kernel<<<dim3(B_NUM / GQ, L_NUM), 256, 0, stream>>>(
        X, K, invK, sArr, idxW, wgtW);
    gather_kernel<<<NTILE, 256, 0, stream>>>(Pp, idxW, wgtW, (float*)d_out);
}